// Round 1
// baseline (21181.049 us; speedup 1.0000x reference)
//
#include <hip/hip_runtime.h>
#include <hip/hip_bf16.h>
#include <math.h>

#define NT 256

static constexpr int B_ = 2;
static constexpr int NCLS_ = 24;

// ---------------- hypernet: w[b, h*128+o, c] = sum_q y[b,q] * tables[h,q,o*1024+c]
__global__ void hyper_k(const float* __restrict__ y, const float* __restrict__ tables,
                        float* __restrict__ wproj) {
    int idx = blockIdx.x * NT + threadIdx.x;      // h*131072 + k, total 2^20
    int h = idx >> 17;
    int k = idx & 131071;
    const float* t = tables + (size_t)h * NCLS_ * 131072 + k;
    float a0 = 0.f, a1 = 0.f;
#pragma unroll
    for (int q = 0; q < NCLS_; q++) {
        float v = t[(size_t)q << 17];
        a0 = fmaf(y[q], v, a0);
        a1 = fmaf(y[NCLS_ + q], v, a1);
    }
    wproj[idx] = a0;
    wproj[(1u << 20) + idx] = a1;
}

// ---------------- dynamic 1x1x1 conv: x0[b,o,s] = sum_c xin[b,c,s] * wproj[b,o,c]
__global__ void conv0_k(const float* __restrict__ xin, const float* __restrict__ wp,
                        float* __restrict__ x0) {
    int o = blockIdx.x, b = blockIdx.y;
    __shared__ float wl[1024];
    for (int i = threadIdx.x; i < 1024; i += NT)
        wl[i] = wp[((size_t)b << 20) + (size_t)o * 1024 + i];
    __syncthreads();
    int s = threadIdx.x;
    if (s < 192) {
        const float* xb = xin + (size_t)b * 1024 * 192 + s;
        float acc = 0.f;
#pragma unroll 8
        for (int c = 0; c < 1024; c++) acc = fmaf(xb[(size_t)c * 192], wl[c], acc);
        x0[((size_t)b * 1024 + o) * 192 + s] = acc;
    }
}

// ---------------- BN stats: per-channel sum/sumsq over (B, spatial)
__global__ void bnstats_k(const float* __restrict__ x, float* __restrict__ sums,
                          int C, int S) {
    int c = blockIdx.x;
    int total = B_ * S;
    float s1 = 0.f, s2 = 0.f;
    for (int e = blockIdx.y * NT + threadIdx.x; e < total; e += gridDim.y * NT) {
        int b = e / S, sp = e - b * S;
        float v = x[((size_t)b * C + c) * S + sp];
        s1 += v;
        s2 = fmaf(v, v, s2);
    }
#pragma unroll
    for (int o = 32; o > 0; o >>= 1) {
        s1 += __shfl_down(s1, o);
        s2 += __shfl_down(s2, o);
    }
    __shared__ float red[4][2];
    int wid = threadIdx.x >> 6, lane = threadIdx.x & 63;
    if (lane == 0) { red[wid][0] = s1; red[wid][1] = s2; }
    __syncthreads();
    if (threadIdx.x == 0) {
        float t1 = 0.f, t2 = 0.f;
        for (int w = 0; w < NT / 64; w++) { t1 += red[w][0]; t2 += red[w][1]; }
        atomicAdd(&sums[2 * c], t1);
        atomicAdd(&sums[2 * c + 1], t2);
    }
}

__global__ void bnfinal_k(const float* __restrict__ sums, const float* __restrict__ g,
                          const float* __restrict__ be, float* __restrict__ sc,
                          float* __restrict__ sh, int C, float invNe) {
    int c = blockIdx.x * NT + threadIdx.x;
    if (c < C) {
        float m = sums[2 * c] * invNe;
        float v = sums[2 * c + 1] * invNe - m * m;
        float s = g[c] * rsqrtf(v + 1e-5f);
        sc[c] = s;
        sh[c] = be[c] - m * s;
    }
}

// ---------------- in-place BN+ReLU apply (float4; S % 4 == 0)
__global__ void bnapply_k(float* __restrict__ x, const float* __restrict__ sc,
                          const float* __restrict__ sh, int C, int S, int total4) {
    int i = blockIdx.x * NT + threadIdx.x;
    if (i >= total4) return;
    int c = ((i * 4) / S) % C;
    float s = sc[c], h = sh[c];
    float4 v = reinterpret_cast<float4*>(x)[i];
    v.x = fmaxf(0.f, fmaf(v.x, s, h));
    v.y = fmaxf(0.f, fmaf(v.y, s, h));
    v.z = fmaxf(0.f, fmaf(v.z, s, h));
    v.w = fmaxf(0.f, fmaf(v.w, s, h));
    reinterpret_cast<float4*>(x)[i] = v;
}

// ---------------- ConvTranspose3d k=4 s=2 p=1, direct gather, weights [CI][CO][4][4][4]
template <int CI, int CO, int DI, int HI, int WI, int CK, bool SIG>
__global__ void convt_k(const float* __restrict__ x, const float* __restrict__ W,
                        const float* __restrict__ bias, float* __restrict__ out) {
    constexpr int DO = 2 * DI, HO = 2 * HI, WO = 2 * WI;
    constexpr int SO = DO * HO * WO, SI = DI * HI * WI;
    int n = blockIdx.z, co = blockIdx.y;
    int sp = blockIdx.x * NT + threadIdx.x;
    int oz = sp / (HO * WO);
    int r = sp - oz * (HO * WO);
    int oy = r / WO;
    int ox = r - oy * WO;

    int offs[8], tap[8];
    {
        int kz0 = (oz + 1) & 1, ky0 = (oy + 1) & 1, kx0 = (ox + 1) & 1;
        int t = 0;
#pragma unroll
        for (int jz = 0; jz < 2; jz++)
#pragma unroll
            for (int jy = 0; jy < 2; jy++)
#pragma unroll
                for (int jx = 0; jx < 2; jx++) {
                    int kz = kz0 + 2 * jz, ky = ky0 + 2 * jy, kx = kx0 + 2 * jx;
                    int iz = (oz + 1 - kz) >> 1, iy = (oy + 1 - ky) >> 1, ix = (ox + 1 - kx) >> 1;
                    bool ok = (unsigned)iz < (unsigned)DI && (unsigned)iy < (unsigned)HI &&
                              (unsigned)ix < (unsigned)WI;
                    offs[t] = ok ? ((iz * HI + iy) * WI + ix) : -1;
                    tap[t] = kz * 16 + ky * 4 + kx;
                    t++;
                }
    }

    __shared__ float wl[CK * 64];
    float acc = bias[co];
    const float* xb = x + (size_t)n * CI * SI;
    for (int c0 = 0; c0 < CI; c0 += CK) {
        __syncthreads();
        for (int i = threadIdx.x; i < CK * 64; i += NT)
            wl[i] = W[((size_t)(c0 + (i >> 6)) * CO + co) * 64 + (i & 63)];
        __syncthreads();
#pragma unroll 4
        for (int cl = 0; cl < CK; cl++) {
            const float* xc = xb + (size_t)(c0 + cl) * SI;
            const float* wr = wl + cl * 64;
#pragma unroll
            for (int t = 0; t < 8; t++) {
                float v = (offs[t] >= 0) ? xc[offs[t]] : 0.f;
                acc = fmaf(v, wr[tap[t]], acc);
            }
        }
    }
    if (SIG) acc = 1.f / (1.f + expf(-acc));
    out[((size_t)n * CO + co) * SO + sp] = acc;
}

extern "C" void kernel_launch(void* const* d_in, const int* in_sizes, int n_in,
                              void* d_out, int out_size, void* d_ws, size_t ws_size,
                              hipStream_t stream) {
    const float* x_in = (const float*)d_in[0];
    const float* y_in = (const float*)d_in[1];
    const float* tables = (const float*)d_in[2];
    const float* g0 = (const float*)d_in[3];
    const float* be0 = (const float*)d_in[4];
    const float* g1 = (const float*)d_in[5];
    const float* be1 = (const float*)d_in[6];
    const float* g2 = (const float*)d_in[7];
    const float* be2 = (const float*)d_in[8];
    const float* g3 = (const float*)d_in[9];
    const float* be3 = (const float*)d_in[10];
    const float* g4 = (const float*)d_in[11];
    const float* be4 = (const float*)d_in[12];
    const float* w1 = (const float*)d_in[13];
    const float* b1 = (const float*)d_in[14];
    const float* w2 = (const float*)d_in[15];
    const float* b2 = (const float*)d_in[16];
    const float* w3 = (const float*)d_in[17];
    const float* b3 = (const float*)d_in[18];
    const float* w4 = (const float*)d_in[19];
    const float* b4 = (const float*)d_in[20];
    const float* w5 = (const float*)d_in[21];
    const float* b5 = (const float*)d_in[22];
    float* out = (float*)d_out;

    // workspace layout (floats), liveness-overlapped: peak = x3 + stats + x4 = ~302MB
    float* ws = (float*)d_ws;
    float* x3 = ws;                               // 25,165,824
    float* sums = ws + 25165824;                  // 2048
    float* sc = ws + 25165824 + 2048;             // 1024
    float* sh = ws + 25165824 + 3072;             // 1024
    float* x4 = ws + 25169920;                    // 50,331,648
    // dead-by-convt4 buffers live inside x4's region:
    float* wproj = x4;                            // 2,097,152
    float* x0 = wproj + 2097152;                  // 393,216
    float* x1 = x0 + 393216;                      // 1,572,864
    float* x2 = x1 + 1572864;                     // 6,291,456

    hyper_k<<<4096, NT, 0, stream>>>(y_in, tables, wproj);
    conv0_k<<<dim3(1024, 2), NT, 0, stream>>>(x_in, wproj, x0);

    // BN0: C=1024, S=192
    hipMemsetAsync(sums, 0, 2 * 1024 * 4, stream);
    bnstats_k<<<dim3(1024, 1), NT, 0, stream>>>(x0, sums, 1024, 192);
    bnfinal_k<<<4, NT, 0, stream>>>(sums, g0, be0, sc, sh, 1024, 1.f / (2 * 192));
    bnapply_k<<<384, NT, 0, stream>>>(x0, sc, sh, 1024, 192, 98304);
    convt_k<1024, 512, 4, 6, 8, 16, false><<<dim3(6, 512, 2), NT, 0, stream>>>(x0, w1, b1, x1);

    // BN1: C=512, S=1536
    hipMemsetAsync(sums, 0, 2 * 512 * 4, stream);
    bnstats_k<<<dim3(512, 2), NT, 0, stream>>>(x1, sums, 512, 1536);
    bnfinal_k<<<2, NT, 0, stream>>>(sums, g1, be1, sc, sh, 512, 1.f / (2 * 1536));
    bnapply_k<<<1536, NT, 0, stream>>>(x1, sc, sh, 512, 1536, 393216);
    convt_k<512, 256, 8, 12, 16, 16, false><<<dim3(48, 256, 2), NT, 0, stream>>>(x1, w2, b2, x2);

    // BN2: C=256, S=12288
    hipMemsetAsync(sums, 0, 2 * 256 * 4, stream);
    bnstats_k<<<dim3(256, 8), NT, 0, stream>>>(x2, sums, 256, 12288);
    bnfinal_k<<<1, NT, 0, stream>>>(sums, g2, be2, sc, sh, 256, 1.f / (2 * 12288));
    bnapply_k<<<6144, NT, 0, stream>>>(x2, sc, sh, 256, 12288, 1572864);
    convt_k<256, 128, 16, 24, 32, 16, false><<<dim3(384, 128, 2), NT, 0, stream>>>(x2, w3, b3, x3);

    // BN3: C=128, S=98304
    hipMemsetAsync(sums, 0, 2 * 128 * 4, stream);
    bnstats_k<<<dim3(128, 32), NT, 0, stream>>>(x3, sums, 128, 98304);
    bnfinal_k<<<1, NT, 0, stream>>>(sums, g3, be3, sc, sh, 128, 1.f / (2 * 98304));
    bnapply_k<<<24576, NT, 0, stream>>>(x3, sc, sh, 128, 98304, 6291456);
    convt_k<128, 32, 32, 48, 64, 16, false><<<dim3(3072, 32, 2), NT, 0, stream>>>(x3, w4, b4, x4);

    // BN4: C=32, S=786432
    hipMemsetAsync(sums, 0, 2 * 32 * 4, stream);
    bnstats_k<<<dim3(32, 256), NT, 0, stream>>>(x4, sums, 32, 786432);
    bnfinal_k<<<1, NT, 0, stream>>>(sums, g4, be4, sc, sh, 32, 1.f / (2 * 786432));
    bnapply_k<<<49152, NT, 0, stream>>>(x4, sc, sh, 32, 786432, 12582912);
    convt_k<32, 1, 64, 96, 128, 32, true><<<dim3(24576, 1, 2), NT, 0, stream>>>(x4, w5, b5, out);
}

// Round 2
// 2839.861 us; speedup vs baseline: 7.4585x; 7.4585x over previous
//
#include <hip/hip_runtime.h>
#include <hip/hip_bf16.h>
#include <math.h>

typedef __attribute__((ext_vector_type(8))) short short8;
typedef __attribute__((ext_vector_type(4))) float f32x4;

__device__ __forceinline__ unsigned short f2bf(float f) {
    unsigned u = __builtin_bit_cast(unsigned, f);
    return (unsigned short)((u + 0x7fffu + ((u >> 16) & 1u)) >> 16);
}
__device__ __forceinline__ float bf2f(unsigned short h) {
    unsigned u = ((unsigned)h) << 16;
    return __builtin_bit_cast(float, u);
}

static constexpr int NCLS_ = 24;

// ---------------- hypernet: wproj[b][h*131072 + o_lo*1024 + ci]
__global__ void hyper_k(const float* __restrict__ y, const float* __restrict__ tables,
                        float* __restrict__ wproj) {
    int idx = blockIdx.x * 256 + threadIdx.x;  // h*131072 + k
    int h = idx >> 17;
    int k = idx & 131071;
    const float* t = tables + (size_t)h * NCLS_ * 131072 + k;
    float a0 = 0.f, a1 = 0.f;
#pragma unroll
    for (int q = 0; q < NCLS_; q++) {
        float v = t[(size_t)q << 17];
        a0 = fmaf(y[q], v, a0);
        a1 = fmaf(y[NCLS_ + q], v, a1);
    }
    wproj[idx] = a0;
    wproj[(1u << 20) + idx] = a1;
}

// ---------------- dynamic 1x1x1 conv -> x0 parity-split channels-last bf16
// x0[(pi*2+b)*24 + qi][1024]
__global__ void conv0_k(const float* __restrict__ xin, const float* __restrict__ wp,
                        unsigned short* __restrict__ x0) {
    int o = blockIdx.x, b = blockIdx.y;
    __shared__ float wl[1024];
    for (int i = threadIdx.x; i < 1024; i += 256)
        wl[i] = wp[((size_t)b << 20) + (size_t)o * 1024 + i];
    __syncthreads();
    int s = threadIdx.x;
    if (s < 192) {
        const float* xb = xin + (size_t)b * 1024 * 192 + s;
        float acc = 0.f;
#pragma unroll 8
        for (int c = 0; c < 1024; c++) acc = fmaf(xb[(size_t)c * 192], wl[c], acc);
        int z = s / 48, rem = s - z * 48, yy = rem / 8, xx = rem - yy * 8;
        int pi = ((z & 1) << 2) | ((yy & 1) << 1) | (xx & 1);
        int qi = ((z >> 1) * 3 + (yy >> 1)) * 4 + (xx >> 1);
        x0[(((size_t)pi * 2 + b) * 24 + qi) * 1024 + o] = f2bf(acc);
    }
}

// ---------------- weight transform: W[ci][co][64 taps] f32 -> Wt[p][co][K] bf16
// K-order: k = ci_hi*64 + j*8 + ci_lo ; tap kd = 1 - pd + 2*jd
template <int CO, int CI>
__global__ void wt_k(const float* __restrict__ W, unsigned short* __restrict__ Wt) {
    int t = blockIdx.x * 256 + threadIdx.x;  // [0, 8*CO*CI)
    int p = t / (CO * CI);
    int rem = t - p * (CO * CI);
    int co = rem / CI;
    int rem2 = rem - co * CI;
    int ci_hi = rem2 >> 3, j = rem2 & 7;
    int pz = p >> 2, py = (p >> 1) & 1, px = p & 1;
    int jz = j >> 2, jy = (j >> 1) & 1, jx = j & 1;
    int tap = (1 - pz + 2 * jz) * 16 + (1 - py + 2 * jy) * 4 + (1 - px + 2 * jx);
    short8 ov;
#pragma unroll
    for (int cl = 0; cl < 8; cl++) {
        float v = W[((size_t)(ci_hi * 8 + cl) * CO + co) * 64 + tap];
        ov[cl] = (short)f2bf(v);
    }
    *(short8*)(Wt + ((size_t)(p * CO + co) * (CI * 8) + ci_hi * 64 + j * 8)) = ov;
}

// ---------------- BN stats (channels-last bf16): sums[ci], sums[C+ci]
__global__ void bnstats2_k(const unsigned short* __restrict__ x, float* __restrict__ sums,
                           int C, int R) {
    int lane = threadIdx.x & 63;
    int wv = threadIdx.x >> 6;
    int ci = blockIdx.x * 64 + lane;
    bool act = ci < C;
    float s1 = 0.f, s2 = 0.f;
    for (int r = blockIdx.y * 4 + wv; r < R; r += gridDim.y * 4) {
        if (act) {
            float v = bf2f(x[(size_t)r * C + ci]);
            s1 += v;
            s2 = fmaf(v, v, s2);
        }
    }
    __shared__ float red[2][4][64];
    red[0][wv][lane] = s1;
    red[1][wv][lane] = s2;
    __syncthreads();
    if (threadIdx.x < 64 && act) {
        float t1 = red[0][0][lane] + red[0][1][lane] + red[0][2][lane] + red[0][3][lane];
        float t2 = red[1][0][lane] + red[1][1][lane] + red[1][2][lane] + red[1][3][lane];
        atomicAdd(&sums[ci], t1);
        atomicAdd(&sums[C + ci], t2);
    }
}

__global__ void bnfinal_k(const float* __restrict__ sums, const float* __restrict__ g,
                          const float* __restrict__ be, float* __restrict__ sc,
                          float* __restrict__ sh, int C, float invN) {
    int c = blockIdx.x * 256 + threadIdx.x;
    if (c < C) {
        float m = sums[c] * invN;
        float v = sums[C + c] * invN - m * m;
        float s = g[c] * rsqrtf(v + 1e-5f);
        sc[c] = s;
        sh[c] = be[c] - m * s;
    }
}

// ---------------- BN apply + ReLU in-place (bf16 x8)
__global__ void bnapply2_k(unsigned short* __restrict__ x, const float* __restrict__ sc,
                           const float* __restrict__ sh, int C, int total8) {
    int i = blockIdx.x * 256 + threadIdx.x;
    if (i >= total8) return;
    int c0 = (i * 8) % C;
    short8 v = *(short8*)(x + (size_t)i * 8);
    short8 ov;
#pragma unroll
    for (int k = 0; k < 8; k++) {
        float f = bf2f((unsigned short)v[k]);
        f = fmaxf(0.f, fmaf(f, sc[c0 + k], sh[c0 + k]));
        ov[k] = (short)f2bf(f);
    }
    *(short8*)(x + (size_t)i * 8) = ov;
}

// ---------------- ConvT as per-parity implicit GEMM via MFMA 16x16x32 bf16
// xin parity-split channels-last: [pin*2+b][SQI][CI]
// out (non-SIG): [p*2+b][SQO=DI*HI*WI][CO]; SIG: real f32 NCDHW out + sigmoid
template <int CO, int CI, int DI, int HI, int WI, int TZ, int TY, int TX, int WM, int BMW, bool SIG>
__global__ __launch_bounds__(256) void convt_mfma(const unsigned short* __restrict__ xin,
                                                  const unsigned short* __restrict__ Wt,
                                                  const float* __restrict__ bias,
                                                  void* __restrict__ xout) {
    constexpr int WN = 4 / WM;
    constexpr int WTZ = TZ / WN, WTY = TY, WTX = TX;
    constexpr int LWTX = (WTX == 8) ? 3 : ((WTX == 4) ? 2 : 1);
    constexpr int LWTY = (WTY == 4) ? 2 : ((WTY == 2) ? 1 : 0);
    constexpr int YS = TX + 1;
    constexpr int ZS = (TY + 1) * (TX + 1);
    constexpr int WINR = (TZ + 1) * ZS;
    constexpr int AROWS = WM * BMW;
    constexpr int MT = (CO + BMW * WM - 1) / (BMW * WM);
    constexpr int MF = BMW / 16;
    constexpr int KT = CI / 8;
    constexpr int HH = HI / 2, WH = WI / 2;
    constexpr int SQI = (DI / 2) * HH * WH;
    constexpr int SQO = DI * HI * WI;
    constexpr int WITER = (WINR + 255) / 256;
    constexpr int AITER = (AROWS * 8 + 255) / 256;

    __shared__ short lw[WINR * 8];
    __shared__ short la[AROWS * 72];  // 144B rows: bank-conflict-free A reads

    const int tid = threadIdx.x;
    const int mt = blockIdx.x % MT;
    const int nt = blockIdx.x / MT;
    constexpr int NTX = WI / TX, NTY = HI / TY;
    const int tx = nt % NTX;
    const int tyz = nt / NTX;
    const int ty = tyz % NTY;
    const int tz = tyz / NTY;
    const int q0z = tz * TZ, q0y = ty * TY, q0x = tx * TX;
    const int p = blockIdx.y;
    const int pz = p >> 2, py = (p >> 1) & 1, px = p & 1;
    const int b = blockIdx.z;

    // window-row staging precompute
    const unsigned short* srcp[WITER];
    int dstw[WITER];
#pragma unroll
    for (int rr = 0; rr < WITER; rr++) {
        int row = tid + rr * 256;
        srcp[rr] = nullptr;
        dstw[rr] = row * 8;
        if (row < WINR) {
            int wz = row / ZS;
            int rm = row - wz * ZS;
            int wy = rm / YS;
            int wx = rm - wy * YS;
            int gz = q0z + pz - 1 + wz, gy = q0y + py - 1 + wy, gx = q0x + px - 1 + wx;
            if ((unsigned)gz < (unsigned)DI && (unsigned)gy < (unsigned)HI &&
                (unsigned)gx < (unsigned)WI) {
                int pin = ((gz & 1) << 2) | ((gy & 1) << 1) | (gx & 1);
                int qin = ((gz >> 1) * HH + (gy >> 1)) * WH + (gx >> 1);
                srcp[rr] = xin + (((size_t)pin * 2 + b) * SQI + qin) * CI;
            }
        }
    }
    // A-row staging precompute
    const unsigned short* asrc[AITER];
    int dsta[AITER];
#pragma unroll
    for (int ar = 0; ar < AITER; ar++) {
        int t2 = tid + ar * 256;
        asrc[ar] = nullptr;
        dsta[ar] = 0;
        if (t2 < AROWS * 8) {
            int row = t2 >> 3, seg = t2 & 7;
            int co = mt * (BMW * WM) + row;
            dsta[ar] = row * 72 + seg * 8;
            if (co < CO) asrc[ar] = Wt + (size_t)(p * CO + co) * (CI * 8) + seg * 8;
        }
    }

    const int lane = tid & 63;
    const int r15 = lane & 15, l4 = lane >> 4;
    const int w = tid >> 6;
    const int wm = (WM == 4) ? w : 0;
    const int wn = (WM == 4) ? 0 : w;
    const int jy = (l4 >> 1) & 1, jx = l4 & 1;

    // per-lane B addresses (shorts), ks=0; ks=1 subtracts ZS*8 (jz=1)
    int baddr[4];
#pragma unroll
    for (int nf = 0; nf < 4; nf++) {
        int n = nf * 16 + r15;
        int qx = n & (WTX - 1);
        int qy = (n >> LWTX) & (WTY - 1);
        int qz = (n >> (LWTX + LWTY)) + wn * WTZ;
        baddr[nf] = ((qz + 1) * ZS + (qy + 1 - jy) * YS + (qx + 1 - jx)) * 8;
    }

    f32x4 acc[MF][4];
#pragma unroll
    for (int mf = 0; mf < MF; mf++) {
        int cobase = mt * (BMW * WM) + wm * BMW + mf * 16 + l4 * 4;
        f32x4 bv;
#pragma unroll
        for (int r = 0; r < 4; r++) bv[r] = (cobase + r < CO) ? bias[cobase + r] : 0.f;
#pragma unroll
        for (int nf = 0; nf < 4; nf++) acc[mf][nf] = bv;
    }

    for (int kt = 0; kt < KT; kt++) {
        __syncthreads();
#pragma unroll
        for (int rr = 0; rr < WITER; rr++) {
            int row = tid + rr * 256;
            if ((WINR % 256 == 0) || row < WINR) {
                short8 v = {0, 0, 0, 0, 0, 0, 0, 0};
                if (srcp[rr]) v = *(const short8*)(srcp[rr] + kt * 8);
                *(short8*)(lw + dstw[rr]) = v;
            }
        }
#pragma unroll
        for (int ar = 0; ar < AITER; ar++) {
            int t2 = tid + ar * 256;
            if (((AROWS * 8) % 256 == 0) || t2 < AROWS * 8) {
                short8 v = {0, 0, 0, 0, 0, 0, 0, 0};
                if (asrc[ar]) v = *(const short8*)(asrc[ar] + kt * 64);
                *(short8*)(la + dsta[ar]) = v;
            }
        }
        __syncthreads();

        short8 af[MF][2], bfr[4][2];
#pragma unroll
        for (int mf = 0; mf < MF; mf++)
#pragma unroll
            for (int ks = 0; ks < 2; ks++)
                af[mf][ks] =
                    *(const short8*)(la + (wm * BMW + mf * 16 + r15) * 72 + ks * 32 + l4 * 8);
#pragma unroll
        for (int nf = 0; nf < 4; nf++)
#pragma unroll
            for (int ks = 0; ks < 2; ks++)
                bfr[nf][ks] = *(const short8*)(lw + baddr[nf] - ks * (ZS * 8));
#pragma unroll
        for (int mf = 0; mf < MF; mf++)
#pragma unroll
            for (int nf = 0; nf < 4; nf++)
#pragma unroll
                for (int ks = 0; ks < 2; ks++)
                    acc[mf][nf] = __builtin_amdgcn_mfma_f32_16x16x32_bf16(
                        af[mf][ks], bfr[nf][ks], acc[mf][nf], 0, 0, 0);
    }

    // epilogue
#pragma unroll
    for (int nf = 0; nf < 4; nf++) {
        int n = nf * 16 + r15;
        int qx = q0x + (n & (WTX - 1));
        int qy = q0y + ((n >> LWTX) & (WTY - 1));
        int qz = q0z + (n >> (LWTX + LWTY)) + wn * WTZ;
        if constexpr (SIG) {
            if (l4 == 0) {
                int oz = 2 * qz + pz, oy = 2 * qy + py, ox = 2 * qx + px;
                float v = acc[0][nf][0];
                v = 1.f / (1.f + __expf(-v));
                ((float*)xout)[(size_t)b * (8 * SQO) + ((size_t)oz * (2 * HI) + oy) * (2 * WI) +
                               ox] = v;
            }
        } else {
            int gq = (qz * HI + qy) * WI + qx;
#pragma unroll
            for (int mf = 0; mf < MF; mf++) {
                int cobase = mt * (BMW * WM) + wm * BMW + mf * 16 + l4 * 4;
                unsigned long long pk = 0;
#pragma unroll
                for (int r = 0; r < 4; r++)
                    pk |= (unsigned long long)f2bf(acc[mf][nf][r]) << (16 * r);
                *(unsigned long long*)((unsigned short*)xout +
                                       (((size_t)p * 2 + b) * SQO + gq) * CO + cobase) = pk;
            }
        }
    }
}

extern "C" void kernel_launch(void* const* d_in, const int* in_sizes, int n_in,
                              void* d_out, int out_size, void* d_ws, size_t ws_size,
                              hipStream_t stream) {
    const float* x_in = (const float*)d_in[0];
    const float* y_in = (const float*)d_in[1];
    const float* tables = (const float*)d_in[2];
    const float* g0 = (const float*)d_in[3];
    const float* be0 = (const float*)d_in[4];
    const float* g1 = (const float*)d_in[5];
    const float* be1 = (const float*)d_in[6];
    const float* g2 = (const float*)d_in[7];
    const float* be2 = (const float*)d_in[8];
    const float* g3 = (const float*)d_in[9];
    const float* be3 = (const float*)d_in[10];
    const float* g4 = (const float*)d_in[11];
    const float* be4 = (const float*)d_in[12];
    const float* w1 = (const float*)d_in[13];
    const float* b1 = (const float*)d_in[14];
    const float* w2 = (const float*)d_in[15];
    const float* b2 = (const float*)d_in[16];
    const float* w3 = (const float*)d_in[17];
    const float* b3 = (const float*)d_in[18];
    const float* w4 = (const float*)d_in[19];
    const float* b4 = (const float*)d_in[20];
    const float* w5 = (const float*)d_in[21];
    const float* b5 = (const float*)d_in[22];
    float* out = (float*)d_out;

    char* base = (char*)d_ws;
    size_t off = 0;
    auto alloc = [&](size_t bytes) -> void* {
        void* r = base + off;
        off += (bytes + 255) & ~(size_t)255;
        return r;
    };
    float* wproj = (float*)alloc(8388608);
    unsigned short* x0 = (unsigned short*)alloc(786432);
    unsigned short* x1 = (unsigned short*)alloc(3145728);
    unsigned short* x2 = (unsigned short*)alloc(12582912);
    unsigned short* x3 = (unsigned short*)alloc(50331648);
    unsigned short* x4 = (unsigned short*)alloc(100663296);
    unsigned short* Wt1 = (unsigned short*)alloc(67108864);
    unsigned short* Wt2 = (unsigned short*)alloc(16777216);
    unsigned short* Wt3 = (unsigned short*)alloc(4194304);
    unsigned short* Wt4 = (unsigned short*)alloc(524288);
    unsigned short* Wt5 = (unsigned short*)alloc(4096);
    float* sums = (float*)alloc(8192);
    float* sc = (float*)alloc(4096);
    float* sh = (float*)alloc(4096);

    hyper_k<<<4096, 256, 0, stream>>>(y_in, tables, wproj);
    conv0_k<<<dim3(1024, 2), 256, 0, stream>>>(x_in, wproj, x0);

    // weight transforms
    wt_k<512, 1024><<<16384, 256, 0, stream>>>(w1, Wt1);
    wt_k<256, 512><<<4096, 256, 0, stream>>>(w2, Wt2);
    wt_k<128, 256><<<1024, 256, 0, stream>>>(w3, Wt3);
    wt_k<32, 128><<<128, 256, 0, stream>>>(w4, Wt4);
    wt_k<1, 32><<<1, 256, 0, stream>>>(w5, Wt5);

    // BN0: C=1024, R=384
    hipMemsetAsync(sums, 0, 2 * 1024 * 4, stream);
    bnstats2_k<<<dim3(16, 24), 256, 0, stream>>>(x0, sums, 1024, 384);
    bnfinal_k<<<4, 256, 0, stream>>>(sums, g0, be0, sc, sh, 1024, 1.f / 384);
    bnapply2_k<<<192, 256, 0, stream>>>(x0, sc, sh, 1024, 49152);
    convt_mfma<512, 1024, 4, 6, 8, 4, 2, 8, 4, 32, false>
        <<<dim3(12, 8, 2), 256, 0, stream>>>(x0, Wt1, b1, x1);

    // BN1: C=512, R=3072
    hipMemsetAsync(sums, 0, 2 * 512 * 4, stream);
    bnstats2_k<<<dim3(8, 64), 256, 0, stream>>>(x1, sums, 512, 3072);
    bnfinal_k<<<2, 256, 0, stream>>>(sums, g1, be1, sc, sh, 512, 1.f / 3072);
    bnapply2_k<<<768, 256, 0, stream>>>(x1, sc, sh, 512, 196608);
    convt_mfma<256, 512, 8, 12, 16, 8, 4, 8, 1, 32, false>
        <<<dim3(48, 8, 2), 256, 0, stream>>>(x1, Wt2, b2, x2);

    // BN2: C=256, R=24576
    hipMemsetAsync(sums, 0, 2 * 256 * 4, stream);
    bnstats2_k<<<dim3(4, 128), 256, 0, stream>>>(x2, sums, 256, 24576);
    bnfinal_k<<<1, 256, 0, stream>>>(sums, g2, be2, sc, sh, 256, 1.f / 24576);
    bnapply2_k<<<3072, 256, 0, stream>>>(x2, sc, sh, 256, 786432);
    convt_mfma<128, 256, 16, 24, 32, 8, 4, 8, 1, 32, false>
        <<<dim3(192, 8, 2), 256, 0, stream>>>(x2, Wt3, b3, x3);

    // BN3: C=128, R=196608
    hipMemsetAsync(sums, 0, 2 * 128 * 4, stream);
    bnstats2_k<<<dim3(2, 128), 256, 0, stream>>>(x3, sums, 128, 196608);
    bnfinal_k<<<1, 256, 0, stream>>>(sums, g3, be3, sc, sh, 128, 1.f / 196608);
    bnapply2_k<<<12288, 256, 0, stream>>>(x3, sc, sh, 128, 3145728);
    convt_mfma<32, 128, 32, 48, 64, 8, 4, 8, 1, 32, false>
        <<<dim3(384, 8, 2), 256, 0, stream>>>(x3, Wt4, b4, x4);

    // BN4: C=32, R=1572864
    hipMemsetAsync(sums, 0, 2 * 32 * 4, stream);
    bnstats2_k<<<dim3(1, 128), 256, 0, stream>>>(x4, sums, 32, 1572864);
    bnfinal_k<<<1, 256, 0, stream>>>(sums, g4, be4, sc, sh, 32, 1.f / 1572864);
    bnapply2_k<<<24576, 256, 0, stream>>>(x4, sc, sh, 32, 6291456);
    convt_mfma<1, 32, 64, 96, 128, 8, 4, 8, 1, 16, true>
        <<<dim3(3072, 8, 2), 256, 0, stream>>>(x4, Wt5, b5, out);
}

// Round 3
// 2282.739 us; speedup vs baseline: 9.2788x; 1.2441x over previous
//
#include <hip/hip_runtime.h>
#include <hip/hip_bf16.h>
#include <math.h>

typedef __attribute__((ext_vector_type(8))) short short8;
typedef __attribute__((ext_vector_type(4))) float f32x4;

__device__ __forceinline__ unsigned short f2bf(float f) {
    unsigned u = __builtin_bit_cast(unsigned, f);
    return (unsigned short)((u + 0x7fffu + ((u >> 16) & 1u)) >> 16);
}
__device__ __forceinline__ float bf2f(unsigned short h) {
    unsigned u = ((unsigned)h) << 16;
    return __builtin_bit_cast(float, u);
}

static constexpr int NCLS_ = 24;

// ---------------- hypernet: wproj[b][h*131072 + o_lo*1024 + ci]
__global__ void hyper_k(const float* __restrict__ y, const float* __restrict__ tables,
                        float* __restrict__ wproj) {
    int idx = blockIdx.x * 256 + threadIdx.x;  // h*131072 + k
    int h = idx >> 17;
    int k = idx & 131071;
    const float* t = tables + (size_t)h * NCLS_ * 131072 + k;
    float a0 = 0.f, a1 = 0.f;
#pragma unroll
    for (int q = 0; q < NCLS_; q++) {
        float v = t[(size_t)q << 17];
        a0 = fmaf(y[q], v, a0);
        a1 = fmaf(y[NCLS_ + q], v, a1);
    }
    wproj[idx] = a0;
    wproj[(1u << 20) + idx] = a1;
}

// ---------------- dynamic 1x1x1 conv -> x0 parity-split channels-last bf16
// x0[(pi*2+b)*24 + qi][1024]
__global__ void conv0_k(const float* __restrict__ xin, const float* __restrict__ wp,
                        unsigned short* __restrict__ x0) {
    int o = blockIdx.x, b = blockIdx.y;
    __shared__ float wl[1024];
    for (int i = threadIdx.x; i < 1024; i += 256)
        wl[i] = wp[((size_t)b << 20) + (size_t)o * 1024 + i];
    __syncthreads();
    int s = threadIdx.x;
    if (s < 192) {
        const float* xb = xin + (size_t)b * 1024 * 192 + s;
        float acc = 0.f;
#pragma unroll 8
        for (int c = 0; c < 1024; c++) acc = fmaf(xb[(size_t)c * 192], wl[c], acc);
        int z = s / 48, rem = s - z * 48, yy = rem / 8, xx = rem - yy * 8;
        int pi = ((z & 1) << 2) | ((yy & 1) << 1) | (xx & 1);
        int qi = ((z >> 1) * 3 + (yy >> 1)) * 4 + (xx >> 1);
        x0[(((size_t)pi * 2 + b) * 24 + qi) * 1024 + o] = f2bf(acc);
    }
}

// ---------------- weight transform: W[ci][co][64 taps] f32 -> Wt[p][co][K] bf16
// K-order: k = ci_hi*64 + j*8 + ci_lo ; tap kd = 1 - pd + 2*jd
template <int CO, int CI>
__global__ void wt_k(const float* __restrict__ W, unsigned short* __restrict__ Wt) {
    int t = blockIdx.x * 256 + threadIdx.x;  // [0, 8*CO*CI)
    int p = t / (CO * CI);
    int rem = t - p * (CO * CI);
    int co = rem / CI;
    int rem2 = rem - co * CI;
    int ci_hi = rem2 >> 3, j = rem2 & 7;
    int pz = p >> 2, py = (p >> 1) & 1, px = p & 1;
    int jz = j >> 2, jy = (j >> 1) & 1, jx = j & 1;
    int tap = (1 - pz + 2 * jz) * 16 + (1 - py + 2 * jy) * 4 + (1 - px + 2 * jx);
    short8 ov;
#pragma unroll
    for (int cl = 0; cl < 8; cl++) {
        float v = W[((size_t)(ci_hi * 8 + cl) * CO + co) * 64 + tap];
        ov[cl] = (short)f2bf(v);
    }
    *(short8*)(Wt + ((size_t)(p * CO + co) * (CI * 8) + ci_hi * 64 + j * 8)) = ov;
}

// ---------------- BN stats v3: vectorized short8 per lane, fixed channel-group per thread
template <int C>
__global__ __launch_bounds__(256) void bnstats3_k(const unsigned short* __restrict__ x,
                                                  float* __restrict__ sums, int R) {
    constexpr int G = C / 8;        // channel groups of 8
    constexpr int REP = 256 / G;    // rows covered per block iteration
    const int t = threadIdx.x;
    const int g = t % G;
    const int rep = t / G;
    float s1[8], s2[8];
#pragma unroll
    for (int k = 0; k < 8; k++) { s1[k] = 0.f; s2[k] = 0.f; }
    for (int r = blockIdx.x * REP + rep; r < R; r += gridDim.x * REP) {
        short8 v = *(const short8*)(x + (size_t)r * C + g * 8);
#pragma unroll
        for (int k = 0; k < 8; k++) {
            float f = bf2f((unsigned short)v[k]);
            s1[k] += f;
            s2[k] = fmaf(f, f, s2[k]);
        }
    }
    __shared__ float red[2][256][8];
#pragma unroll
    for (int k = 0; k < 8; k++) { red[0][t][k] = s1[k]; red[1][t][k] = s2[k]; }
    __syncthreads();
#pragma unroll
    for (int step = 128; step >= 1; step >>= 1) {
        if (step >= G) {
            if (t < step) {
#pragma unroll
                for (int k = 0; k < 8; k++) {
                    red[0][t][k] += red[0][t + step][k];
                    red[1][t][k] += red[1][t + step][k];
                }
            }
            __syncthreads();
        }
    }
    if (t < G) {
#pragma unroll
        for (int k = 0; k < 8; k++) {
            atomicAdd(&sums[t * 8 + k], red[0][t][k]);
            atomicAdd(&sums[C + t * 8 + k], red[1][t][k]);
        }
    }
}

__global__ void bnfinal_k(const float* __restrict__ sums, const float* __restrict__ g,
                          const float* __restrict__ be, float* __restrict__ sc,
                          float* __restrict__ sh, int C, float invN) {
    int c = blockIdx.x * 256 + threadIdx.x;
    if (c < C) {
        float m = sums[c] * invN;
        float v = sums[C + c] * invN - m * m;
        float s = g[c] * rsqrtf(v + 1e-5f);
        sc[c] = s;
        sh[c] = be[c] - m * s;
    }
}

// ---------------- BN apply + ReLU in-place (bf16 x8)
__global__ void bnapply2_k(unsigned short* __restrict__ x, const float* __restrict__ sc,
                           const float* __restrict__ sh, int C, int total8) {
    int i = blockIdx.x * 256 + threadIdx.x;
    if (i >= total8) return;
    int c0 = (i * 8) % C;
    short8 v = *(short8*)(x + (size_t)i * 8);
    short8 ov;
#pragma unroll
    for (int k = 0; k < 8; k++) {
        float f = bf2f((unsigned short)v[k]);
        f = fmaxf(0.f, fmaf(f, sc[c0 + k], sh[c0 + k]));
        ov[k] = (short)f2bf(f);
    }
    *(short8*)(x + (size_t)i * 8) = ov;
}

// ---------------- ConvT as per-parity implicit GEMM via MFMA 16x16x32 bf16
// xin parity-split channels-last: [pin*2+b][SQI][CI]
// out (non-SIG): [p*2+b][SQO=DI*HI*WI][CO]; SIG: real f32 NCDHW out + sigmoid
template <int CO, int CI, int DI, int HI, int WI, int TZ, int TY, int TX, int WM, int BMW, bool SIG>
__global__ __launch_bounds__(256) void convt_mfma(const unsigned short* __restrict__ xin,
                                                  const unsigned short* __restrict__ Wt,
                                                  const float* __restrict__ bias,
                                                  void* __restrict__ xout) {
    constexpr int WN = 4 / WM;
    constexpr int WTZ = TZ / WN, WTY = TY, WTX = TX;
    constexpr int LWTX = (WTX == 8) ? 3 : ((WTX == 4) ? 2 : 1);
    constexpr int LWTY = (WTY == 4) ? 2 : ((WTY == 2) ? 1 : 0);
    constexpr int YS = TX + 1;
    constexpr int ZS = (TY + 1) * (TX + 1);
    constexpr int WINR = (TZ + 1) * ZS;
    constexpr int AROWS = WM * BMW;
    constexpr int MT = (CO + BMW * WM - 1) / (BMW * WM);
    constexpr int MF = BMW / 16;
    constexpr int KT = CI / 8;
    constexpr int HH = HI / 2, WH = WI / 2;
    constexpr int SQI = (DI / 2) * HH * WH;
    constexpr int SQO = DI * HI * WI;
    constexpr int WITER = (WINR + 255) / 256;
    constexpr int AITER = (AROWS * 8 + 255) / 256;

    __shared__ short lw[WINR * 8];
    __shared__ short la[AROWS * 72];  // 144B rows: bank-conflict-free A reads

    const int tid = threadIdx.x;
    const int mt = blockIdx.x % MT;
    const int nt = blockIdx.x / MT;
    constexpr int NTX = WI / TX, NTY = HI / TY;
    const int tx = nt % NTX;
    const int tyz = nt / NTX;
    const int ty = tyz % NTY;
    const int tz = tyz / NTY;
    const int q0z = tz * TZ, q0y = ty * TY, q0x = tx * TX;
    const int p = blockIdx.y;
    const int pz = p >> 2, py = (p >> 1) & 1, px = p & 1;
    const int b = blockIdx.z;

    // window-row staging precompute
    const unsigned short* srcp[WITER];
    int dstw[WITER];
#pragma unroll
    for (int rr = 0; rr < WITER; rr++) {
        int row = tid + rr * 256;
        srcp[rr] = nullptr;
        dstw[rr] = row * 8;
        if (row < WINR) {
            int wz = row / ZS;
            int rm = row - wz * ZS;
            int wy = rm / YS;
            int wx = rm - wy * YS;
            int gz = q0z + pz - 1 + wz, gy = q0y + py - 1 + wy, gx = q0x + px - 1 + wx;
            if ((unsigned)gz < (unsigned)DI && (unsigned)gy < (unsigned)HI &&
                (unsigned)gx < (unsigned)WI) {
                int pin = ((gz & 1) << 2) | ((gy & 1) << 1) | (gx & 1);
                int qin = ((gz >> 1) * HH + (gy >> 1)) * WH + (gx >> 1);
                srcp[rr] = xin + (((size_t)pin * 2 + b) * SQI + qin) * CI;
            }
        }
    }
    // A-row staging precompute
    const unsigned short* asrc[AITER];
    int dsta[AITER];
#pragma unroll
    for (int ar = 0; ar < AITER; ar++) {
        int t2 = tid + ar * 256;
        asrc[ar] = nullptr;
        dsta[ar] = 0;
        if (t2 < AROWS * 8) {
            int row = t2 >> 3, seg = t2 & 7;
            int co = mt * (BMW * WM) + row;
            dsta[ar] = row * 72 + seg * 8;
            if (co < CO) asrc[ar] = Wt + (size_t)(p * CO + co) * (CI * 8) + seg * 8;
        }
    }

    const int lane = tid & 63;
    const int r15 = lane & 15, l4 = lane >> 4;
    const int w = tid >> 6;
    const int wm = (WM == 4) ? w : 0;
    const int wn = (WM == 4) ? 0 : w;
    const int jy = (l4 >> 1) & 1, jx = l4 & 1;

    // per-lane B addresses (shorts), ks=0; ks=1 subtracts ZS*8 (jz=1)
    int baddr[4];
#pragma unroll
    for (int nf = 0; nf < 4; nf++) {
        int n = nf * 16 + r15;
        int qx = n & (WTX - 1);
        int qy = (n >> LWTX) & (WTY - 1);
        int qz = (n >> (LWTX + LWTY)) + wn * WTZ;
        baddr[nf] = ((qz + 1) * ZS + (qy + 1 - jy) * YS + (qx + 1 - jx)) * 8;
    }

    f32x4 acc[MF][4];
#pragma unroll
    for (int mf = 0; mf < MF; mf++) {
        int cobase = mt * (BMW * WM) + wm * BMW + mf * 16 + l4 * 4;
        f32x4 bv;
#pragma unroll
        for (int r = 0; r < 4; r++) bv[r] = (cobase + r < CO) ? bias[cobase + r] : 0.f;
#pragma unroll
        for (int nf = 0; nf < 4; nf++) acc[mf][nf] = bv;
    }

    for (int kt = 0; kt < KT; kt++) {
        __syncthreads();
#pragma unroll
        for (int rr = 0; rr < WITER; rr++) {
            int row = tid + rr * 256;
            if ((WINR % 256 == 0) || row < WINR) {
                short8 v = {0, 0, 0, 0, 0, 0, 0, 0};
                if (srcp[rr]) v = *(const short8*)(srcp[rr] + kt * 8);
                *(short8*)(lw + dstw[rr]) = v;
            }
        }
#pragma unroll
        for (int ar = 0; ar < AITER; ar++) {
            int t2 = tid + ar * 256;
            if (((AROWS * 8) % 256 == 0) || t2 < AROWS * 8) {
                short8 v = {0, 0, 0, 0, 0, 0, 0, 0};
                if (asrc[ar]) v = *(const short8*)(asrc[ar] + kt * 64);
                *(short8*)(la + dsta[ar]) = v;
            }
        }
        __syncthreads();

        short8 af[MF][2], bfr[4][2];
#pragma unroll
        for (int mf = 0; mf < MF; mf++)
#pragma unroll
            for (int ks = 0; ks < 2; ks++)
                af[mf][ks] =
                    *(const short8*)(la + (wm * BMW + mf * 16 + r15) * 72 + ks * 32 + l4 * 8);
#pragma unroll
        for (int nf = 0; nf < 4; nf++)
#pragma unroll
            for (int ks = 0; ks < 2; ks++)
                bfr[nf][ks] = *(const short8*)(lw + baddr[nf] - ks * (ZS * 8));
#pragma unroll
        for (int mf = 0; mf < MF; mf++)
#pragma unroll
            for (int nf = 0; nf < 4; nf++)
#pragma unroll
                for (int ks = 0; ks < 2; ks++)
                    acc[mf][nf] = __builtin_amdgcn_mfma_f32_16x16x32_bf16(
                        af[mf][ks], bfr[nf][ks], acc[mf][nf], 0, 0, 0);
    }

    // epilogue
#pragma unroll
    for (int nf = 0; nf < 4; nf++) {
        int n = nf * 16 + r15;
        int qx = q0x + (n & (WTX - 1));
        int qy = q0y + ((n >> LWTX) & (WTY - 1));
        int qz = q0z + (n >> (LWTX + LWTY)) + wn * WTZ;
        if constexpr (SIG) {
            if (l4 == 0) {
                int oz = 2 * qz + pz, oy = 2 * qy + py, ox = 2 * qx + px;
                float v = acc[0][nf][0];
                v = 1.f / (1.f + __expf(-v));
                ((float*)xout)[(size_t)b * (8 * SQO) + ((size_t)oz * (2 * HI) + oy) * (2 * WI) +
                               ox] = v;
            }
        } else {
            int gq = (qz * HI + qy) * WI + qx;
#pragma unroll
            for (int mf = 0; mf < MF; mf++) {
                int cobase = mt * (BMW * WM) + wm * BMW + mf * 16 + l4 * 4;
                unsigned long long pk = 0;
#pragma unroll
                for (int r = 0; r < 4; r++)
                    pk |= (unsigned long long)f2bf(acc[mf][nf][r]) << (16 * r);
                *(unsigned long long*)((unsigned short*)xout +
                                       (((size_t)p * 2 + b) * SQO + gq) * CO + cobase) = pk;
            }
        }
    }
}

extern "C" void kernel_launch(void* const* d_in, const int* in_sizes, int n_in,
                              void* d_out, int out_size, void* d_ws, size_t ws_size,
                              hipStream_t stream) {
    const float* x_in = (const float*)d_in[0];
    const float* y_in = (const float*)d_in[1];
    const float* tables = (const float*)d_in[2];
    const float* g0 = (const float*)d_in[3];
    const float* be0 = (const float*)d_in[4];
    const float* g1 = (const float*)d_in[5];
    const float* be1 = (const float*)d_in[6];
    const float* g2 = (const float*)d_in[7];
    const float* be2 = (const float*)d_in[8];
    const float* g3 = (const float*)d_in[9];
    const float* be3 = (const float*)d_in[10];
    const float* g4 = (const float*)d_in[11];
    const float* be4 = (const float*)d_in[12];
    const float* w1 = (const float*)d_in[13];
    const float* b1 = (const float*)d_in[14];
    const float* w2 = (const float*)d_in[15];
    const float* b2 = (const float*)d_in[16];
    const float* w3 = (const float*)d_in[17];
    const float* b3 = (const float*)d_in[18];
    const float* w4 = (const float*)d_in[19];
    const float* b4 = (const float*)d_in[20];
    const float* w5 = (const float*)d_in[21];
    const float* b5 = (const float*)d_in[22];
    float* out = (float*)d_out;

    char* base = (char*)d_ws;
    size_t off = 0;
    auto alloc = [&](size_t bytes) -> void* {
        void* r = base + off;
        off += (bytes + 255) & ~(size_t)255;
        return r;
    };
    float* wproj = (float*)alloc(8388608);
    unsigned short* x0 = (unsigned short*)alloc(786432);
    unsigned short* x1 = (unsigned short*)alloc(3145728);
    unsigned short* x2 = (unsigned short*)alloc(12582912);
    unsigned short* x3 = (unsigned short*)alloc(50331648);
    unsigned short* x4 = (unsigned short*)alloc(100663296);
    unsigned short* Wt1 = (unsigned short*)alloc(67108864);
    unsigned short* Wt2 = (unsigned short*)alloc(16777216);
    unsigned short* Wt3 = (unsigned short*)alloc(4194304);
    unsigned short* Wt4 = (unsigned short*)alloc(524288);
    unsigned short* Wt5 = (unsigned short*)alloc(4096);
    float* sums = (float*)alloc(8192);
    float* sc = (float*)alloc(4096);
    float* sh = (float*)alloc(4096);

    hyper_k<<<4096, 256, 0, stream>>>(y_in, tables, wproj);
    conv0_k<<<dim3(1024, 2), 256, 0, stream>>>(x_in, wproj, x0);

    // weight transforms
    wt_k<512, 1024><<<16384, 256, 0, stream>>>(w1, Wt1);
    wt_k<256, 512><<<4096, 256, 0, stream>>>(w2, Wt2);
    wt_k<128, 256><<<1024, 256, 0, stream>>>(w3, Wt3);
    wt_k<32, 128><<<128, 256, 0, stream>>>(w4, Wt4);
    wt_k<1, 32><<<1, 256, 0, stream>>>(w5, Wt5);

    // BN0: C=1024, R=384
    hipMemsetAsync(sums, 0, 2 * 1024 * 4, stream);
    bnstats3_k<1024><<<192, 256, 0, stream>>>(x0, sums, 384);
    bnfinal_k<<<4, 256, 0, stream>>>(sums, g0, be0, sc, sh, 1024, 1.f / 384);
    bnapply2_k<<<192, 256, 0, stream>>>(x0, sc, sh, 1024, 49152);
    convt_mfma<512, 1024, 4, 6, 8, 4, 2, 8, 4, 32, false>
        <<<dim3(12, 8, 2), 256, 0, stream>>>(x0, Wt1, b1, x1);

    // BN1: C=512, R=3072
    hipMemsetAsync(sums, 0, 2 * 512 * 4, stream);
    bnstats3_k<512><<<512, 256, 0, stream>>>(x1, sums, 3072);
    bnfinal_k<<<2, 256, 0, stream>>>(sums, g1, be1, sc, sh, 512, 1.f / 3072);
    bnapply2_k<<<768, 256, 0, stream>>>(x1, sc, sh, 512, 196608);
    convt_mfma<256, 512, 8, 12, 16, 8, 4, 8, 1, 32, false>
        <<<dim3(48, 8, 2), 256, 0, stream>>>(x1, Wt2, b2, x2);

    // BN2: C=256, R=24576
    hipMemsetAsync(sums, 0, 2 * 256 * 4, stream);
    bnstats3_k<256><<<512, 256, 0, stream>>>(x2, sums, 24576);
    bnfinal_k<<<1, 256, 0, stream>>>(sums, g2, be2, sc, sh, 256, 1.f / 24576);
    bnapply2_k<<<3072, 256, 0, stream>>>(x2, sc, sh, 256, 786432);
    convt_mfma<128, 256, 16, 24, 32, 8, 4, 8, 1, 32, false>
        <<<dim3(192, 8, 2), 256, 0, stream>>>(x2, Wt3, b3, x3);

    // BN3: C=128, R=196608
    hipMemsetAsync(sums, 0, 2 * 128 * 4, stream);
    bnstats3_k<128><<<512, 256, 0, stream>>>(x3, sums, 196608);
    bnfinal_k<<<1, 256, 0, stream>>>(sums, g3, be3, sc, sh, 128, 1.f / 196608);
    bnapply2_k<<<12288, 256, 0, stream>>>(x3, sc, sh, 128, 3145728);
    convt_mfma<32, 128, 32, 48, 64, 8, 4, 8, 1, 32, false>
        <<<dim3(384, 8, 2), 256, 0, stream>>>(x3, Wt4, b4, x4);

    // BN4: C=32, R=1572864
    hipMemsetAsync(sums, 0, 2 * 32 * 4, stream);
    bnstats3_k<32><<<512, 256, 0, stream>>>(x4, sums, 1572864);
    bnfinal_k<<<1, 256, 0, stream>>>(sums, g4, be4, sc, sh, 32, 1.f / 1572864);
    bnapply2_k<<<24576, 256, 0, stream>>>(x4, sc, sh, 32, 6291456);
    convt_mfma<1, 32, 64, 96, 128, 8, 4, 8, 1, 16, true>
        <<<dim3(3072, 8, 2), 256, 0, stream>>>(x4, Wt5, b5, out);
}

// Round 5
// 2015.900 us; speedup vs baseline: 10.5070x; 1.1324x over previous
//
#include <hip/hip_runtime.h>
#include <hip/hip_bf16.h>
#include <math.h>

typedef __attribute__((ext_vector_type(8))) short short8;
typedef __attribute__((ext_vector_type(4))) float f32x4;

__device__ __forceinline__ unsigned short f2bf(float f) {
    unsigned u = __builtin_bit_cast(unsigned, f);
    return (unsigned short)((u + 0x7fffu + ((u >> 16) & 1u)) >> 16);
}
__device__ __forceinline__ float bf2f(unsigned short h) {
    unsigned u = ((unsigned)h) << 16;
    return __builtin_bit_cast(float, u);
}

static constexpr int NCLS_ = 24;

// ---------------- hypernet: wproj[b][h*131072 + o_lo*1024 + ci]
__global__ void hyper_k(const float* __restrict__ y, const float* __restrict__ tables,
                        float* __restrict__ wproj) {
    int idx = blockIdx.x * 256 + threadIdx.x;  // h*131072 + k
    int h = idx >> 17;
    int k = idx & 131071;
    const float* t = tables + (size_t)h * NCLS_ * 131072 + k;
    float a0 = 0.f, a1 = 0.f;
#pragma unroll
    for (int q = 0; q < NCLS_; q++) {
        float v = t[(size_t)q << 17];
        a0 = fmaf(y[q], v, a0);
        a1 = fmaf(y[NCLS_ + q], v, a1);
    }
    wproj[idx] = a0;
    wproj[(1u << 20) + idx] = a1;
}

// ---------------- dynamic 1x1x1 conv -> x0 parity-split channels-last bf16
__global__ void conv0_k(const float* __restrict__ xin, const float* __restrict__ wp,
                        unsigned short* __restrict__ x0) {
    int o = blockIdx.x, b = blockIdx.y;
    __shared__ float wl[1024];
    for (int i = threadIdx.x; i < 1024; i += 256)
        wl[i] = wp[((size_t)b << 20) + (size_t)o * 1024 + i];
    __syncthreads();
    int s = threadIdx.x;
    if (s < 192) {
        const float* xb = xin + (size_t)b * 1024 * 192 + s;
        float acc = 0.f;
#pragma unroll 8
        for (int c = 0; c < 1024; c++) acc = fmaf(xb[(size_t)c * 192], wl[c], acc);
        int z = s / 48, rem = s - z * 48, yy = rem / 8, xx = rem - yy * 8;
        int pi = ((z & 1) << 2) | ((yy & 1) << 1) | (xx & 1);
        int qi = ((z >> 1) * 3 + (yy >> 1)) * 4 + (xx >> 1);
        x0[(((size_t)pi * 2 + b) * 24 + qi) * 1024 + o] = f2bf(acc);
    }
}

// ---------------- weight transform: W[ci][co][64 taps] f32 -> Wt[p][co][K] bf16
template <int CO, int CI>
__global__ void wt_k(const float* __restrict__ W, unsigned short* __restrict__ Wt) {
    int t = blockIdx.x * 256 + threadIdx.x;  // [0, 8*CO*CI)
    int p = t / (CO * CI);
    int rem = t - p * (CO * CI);
    int co = rem / CI;
    int rem2 = rem - co * CI;
    int ci_hi = rem2 >> 3, j = rem2 & 7;
    int pz = p >> 2, py = (p >> 1) & 1, px = p & 1;
    int jz = j >> 2, jy = (j >> 1) & 1, jx = j & 1;
    int tap = (1 - pz + 2 * jz) * 16 + (1 - py + 2 * jy) * 4 + (1 - px + 2 * jx);
    short8 ov;
#pragma unroll
    for (int cl = 0; cl < 8; cl++) {
        float v = W[((size_t)(ci_hi * 8 + cl) * CO + co) * 64 + tap];
        ov[cl] = (short)f2bf(v);
    }
    *(short8*)(Wt + ((size_t)(p * CO + co) * (CI * 8) + ci_hi * 64 + j * 8)) = ov;
}

// ---------------- BN stats: vectorized short8 per lane, fixed channel-group per thread
template <int C>
__global__ __launch_bounds__(256) void bnstats3_k(const unsigned short* __restrict__ x,
                                                  float* __restrict__ sums, int R) {
    constexpr int G = C / 8;
    constexpr int REP = 256 / G;
    const int t = threadIdx.x;
    const int g = t % G;
    const int rep = t / G;
    float s1[8], s2[8];
#pragma unroll
    for (int k = 0; k < 8; k++) { s1[k] = 0.f; s2[k] = 0.f; }
    for (int r = blockIdx.x * REP + rep; r < R; r += gridDim.x * REP) {
        short8 v = *(const short8*)(x + (size_t)r * C + g * 8);
#pragma unroll
        for (int k = 0; k < 8; k++) {
            float f = bf2f((unsigned short)v[k]);
            s1[k] += f;
            s2[k] = fmaf(f, f, s2[k]);
        }
    }
    __shared__ float red[2][256][8];
#pragma unroll
    for (int k = 0; k < 8; k++) { red[0][t][k] = s1[k]; red[1][t][k] = s2[k]; }
    __syncthreads();
#pragma unroll
    for (int step = 128; step >= 1; step >>= 1) {
        if (step >= G) {
            if (t < step) {
#pragma unroll
                for (int k = 0; k < 8; k++) {
                    red[0][t][k] += red[0][t + step][k];
                    red[1][t][k] += red[1][t + step][k];
                }
            }
            __syncthreads();
        }
    }
    if (t < G) {
#pragma unroll
        for (int k = 0; k < 8; k++) {
            atomicAdd(&sums[t * 8 + k], red[0][t][k]);
            atomicAdd(&sums[C + t * 8 + k], red[1][t][k]);
        }
    }
}

__global__ void bnfinal_k(const float* __restrict__ sums, const float* __restrict__ g,
                          const float* __restrict__ be, float* __restrict__ sc,
                          float* __restrict__ sh, int C, float invN) {
    int c = blockIdx.x * 256 + threadIdx.x;
    if (c < C) {
        float m = sums[c] * invN;
        float v = sums[C + c] * invN - m * m;
        float s = g[c] * rsqrtf(v + 1e-5f);
        sc[c] = s;
        sh[c] = be[c] - m * s;
    }
}

// ---------------- BN apply + ReLU in-place (bf16 x8)
__global__ void bnapply2_k(unsigned short* __restrict__ x, const float* __restrict__ sc,
                           const float* __restrict__ sh, int C, int total8) {
    int i = blockIdx.x * 256 + threadIdx.x;
    if (i >= total8) return;
    int c0 = (i * 8) % C;
    short8 v = *(short8*)(x + (size_t)i * 8);
    short8 ov;
#pragma unroll
    for (int k = 0; k < 8; k++) {
        float f = bf2f((unsigned short)v[k]);
        f = fmaxf(0.f, fmaf(f, sc[c0 + k], sh[c0 + k]));
        ov[k] = (short)f2bf(f);
    }
    *(short8*)(x + (size_t)i * 8) = ov;
}

// ---------------- per-parity implicit-GEMM convT (stages 1-3; weights big, input L2-small)
template <int CO, int CI, int DI, int HI, int WI, int TZ, int TY, int TX, int WM, int BMW, bool SIG>
__global__ __launch_bounds__(256) void convt_mfma(const unsigned short* __restrict__ xin,
                                                  const unsigned short* __restrict__ Wt,
                                                  const float* __restrict__ bias,
                                                  void* __restrict__ xout) {
    constexpr int WN = 4 / WM;
    constexpr int WTZ = TZ / WN, WTY = TY, WTX = TX;
    constexpr int LWTX = (WTX == 8) ? 3 : ((WTX == 4) ? 2 : 1);
    constexpr int LWTY = (WTY == 4) ? 2 : ((WTY == 2) ? 1 : 0);
    constexpr int YS = TX + 1;
    constexpr int ZS = (TY + 1) * (TX + 1);
    constexpr int WINR = (TZ + 1) * ZS;
    constexpr int AROWS = WM * BMW;
    constexpr int MT = (CO + BMW * WM - 1) / (BMW * WM);
    constexpr int MF = BMW / 16;
    constexpr int KT = CI / 8;
    constexpr int HH = HI / 2, WH = WI / 2;
    constexpr int SQI = (DI / 2) * HH * WH;
    constexpr int SQO = DI * HI * WI;
    constexpr int WITER = (WINR + 255) / 256;
    constexpr int AITER = (AROWS * 8 + 255) / 256;

    __shared__ short lw[WINR * 8];
    __shared__ short la[AROWS * 72];

    const int tid = threadIdx.x;
    const int mt = blockIdx.x % MT;
    const int nt = blockIdx.x / MT;
    constexpr int NTX = WI / TX, NTY = HI / TY;
    const int tx = nt % NTX;
    const int tyz = nt / NTX;
    const int ty = tyz % NTY;
    const int tz = tyz / NTY;
    const int q0z = tz * TZ, q0y = ty * TY, q0x = tx * TX;
    const int p = blockIdx.y;
    const int pz = p >> 2, py = (p >> 1) & 1, px = p & 1;
    const int b = blockIdx.z;

    const unsigned short* srcp[WITER];
    int dstw[WITER];
#pragma unroll
    for (int rr = 0; rr < WITER; rr++) {
        int row = tid + rr * 256;
        srcp[rr] = nullptr;
        dstw[rr] = row * 8;
        if (row < WINR) {
            int wz = row / ZS;
            int rm = row - wz * ZS;
            int wy = rm / YS;
            int wx = rm - wy * YS;
            int gz = q0z + pz - 1 + wz, gy = q0y + py - 1 + wy, gx = q0x + px - 1 + wx;
            if ((unsigned)gz < (unsigned)DI && (unsigned)gy < (unsigned)HI &&
                (unsigned)gx < (unsigned)WI) {
                int pin = ((gz & 1) << 2) | ((gy & 1) << 1) | (gx & 1);
                int qin = ((gz >> 1) * HH + (gy >> 1)) * WH + (gx >> 1);
                srcp[rr] = xin + (((size_t)pin * 2 + b) * SQI + qin) * CI;
            }
        }
    }
    const unsigned short* asrc[AITER];
    int dsta[AITER];
#pragma unroll
    for (int ar = 0; ar < AITER; ar++) {
        int t2 = tid + ar * 256;
        asrc[ar] = nullptr;
        dsta[ar] = 0;
        if (t2 < AROWS * 8) {
            int row = t2 >> 3, seg = t2 & 7;
            int co = mt * (BMW * WM) + row;
            dsta[ar] = row * 72 + seg * 8;
            if (co < CO) asrc[ar] = Wt + (size_t)(p * CO + co) * (CI * 8) + seg * 8;
        }
    }

    const int lane = tid & 63;
    const int r15 = lane & 15, l4 = lane >> 4;
    const int w = tid >> 6;
    const int wm = (WM == 4) ? w : 0;
    const int wn = (WM == 4) ? 0 : w;
    const int jy = (l4 >> 1) & 1, jx = l4 & 1;

    int baddr[4];
#pragma unroll
    for (int nf = 0; nf < 4; nf++) {
        int n = nf * 16 + r15;
        int qx = n & (WTX - 1);
        int qy = (n >> LWTX) & (WTY - 1);
        int qz = (n >> (LWTX + LWTY)) + wn * WTZ;
        baddr[nf] = ((qz + 1) * ZS + (qy + 1 - jy) * YS + (qx + 1 - jx)) * 8;
    }

    f32x4 acc[MF][4];
#pragma unroll
    for (int mf = 0; mf < MF; mf++) {
        int cobase = mt * (BMW * WM) + wm * BMW + mf * 16 + l4 * 4;
        f32x4 bv;
#pragma unroll
        for (int r = 0; r < 4; r++) bv[r] = (cobase + r < CO) ? bias[cobase + r] : 0.f;
#pragma unroll
        for (int nf = 0; nf < 4; nf++) acc[mf][nf] = bv;
    }

    for (int kt = 0; kt < KT; kt++) {
        __syncthreads();
#pragma unroll
        for (int rr = 0; rr < WITER; rr++) {
            int row = tid + rr * 256;
            if ((WINR % 256 == 0) || row < WINR) {
                short8 v = {0, 0, 0, 0, 0, 0, 0, 0};
                if (srcp[rr]) v = *(const short8*)(srcp[rr] + kt * 8);
                *(short8*)(lw + dstw[rr]) = v;
            }
        }
#pragma unroll
        for (int ar = 0; ar < AITER; ar++) {
            int t2 = tid + ar * 256;
            if (((AROWS * 8) % 256 == 0) || t2 < AROWS * 8) {
                short8 v = {0, 0, 0, 0, 0, 0, 0, 0};
                if (asrc[ar]) v = *(const short8*)(asrc[ar] + kt * 64);
                *(short8*)(la + dsta[ar]) = v;
            }
        }
        __syncthreads();

        short8 af[MF][2], bfr[4][2];
#pragma unroll
        for (int mf = 0; mf < MF; mf++)
#pragma unroll
            for (int ks = 0; ks < 2; ks++)
                af[mf][ks] =
                    *(const short8*)(la + (wm * BMW + mf * 16 + r15) * 72 + ks * 32 + l4 * 8);
#pragma unroll
        for (int nf = 0; nf < 4; nf++)
#pragma unroll
            for (int ks = 0; ks < 2; ks++)
                bfr[nf][ks] = *(const short8*)(lw + baddr[nf] - ks * (ZS * 8));
#pragma unroll
        for (int mf = 0; mf < MF; mf++)
#pragma unroll
            for (int nf = 0; nf < 4; nf++)
#pragma unroll
                for (int ks = 0; ks < 2; ks++)
                    acc[mf][nf] = __builtin_amdgcn_mfma_f32_16x16x32_bf16(
                        af[mf][ks], bfr[nf][ks], acc[mf][nf], 0, 0, 0);
    }

#pragma unroll
    for (int nf = 0; nf < 4; nf++) {
        int n = nf * 16 + r15;
        int qx = q0x + (n & (WTX - 1));
        int qy = q0y + ((n >> LWTX) & (WTY - 1));
        int qz = q0z + (n >> (LWTX + LWTY)) + wn * WTZ;
        int gq = (qz * HI + qy) * WI + qx;
#pragma unroll
        for (int mf = 0; mf < MF; mf++) {
            int cobase = mt * (BMW * WM) + wm * BMW + mf * 16 + l4 * 4;
            unsigned long long pk = 0;
#pragma unroll
            for (int r = 0; r < 4; r++)
                pk |= (unsigned long long)f2bf(acc[mf][nf][r]) << (16 * r);
            *(unsigned long long*)((unsigned short*)xout +
                                   (((size_t)p * 2 + b) * SQO + gq) * CO + cobase) = pk;
        }
    }
}

// ---------------- shared-window convT (stages 4-5; weights L2-tiny, input big)
// One block: spatial q-tile x ALL 8 output parities. Window staged once in LDS.
// A-fragments loaded per-lane from global (weights L2-resident -> no LDS A).
template <int CO, int CI, int DI, int HI, int WI, int TZ, int TY, int TX, int BM, bool SIG>
__global__ __launch_bounds__(256) void convt_mfma2(const unsigned short* __restrict__ xin,
                                                   const unsigned short* __restrict__ Wt,
                                                   const float* __restrict__ bias,
                                                   void* __restrict__ xout) {
    constexpr int WZ = TZ + 2, WY = TY + 2, WX = TX + 2;
    constexpr int WINR = WZ * WY * WX;
    constexpr int TQ = TZ * TY * TX;
    constexpr int SF = TQ / 16;
    constexpr int MF = BM / 16;
    constexpr int MT = (CO + BM - 1) / BM;
    constexpr int KT = CI / 8;
    constexpr int HH = HI / 2, WH = WI / 2;
    constexpr int SQI = (DI / 2) * HH * WH;
    constexpr int SQO = DI * HI * WI;
    static_assert(WINR <= 256, "window must fit one staging pass");

    __shared__ short lw[WINR * 8];

    const int tid = threadIdx.x;
    const int bx = blockIdx.x;
    const int mt = bx % MT;
    const int tile = bx / MT;
    constexpr int NTX = WI / TX, NTY = HI / TY;
    const int tx = tile % NTX;
    const int tyz = tile / NTX;
    const int ty = tyz % NTY;
    const int tz = tyz / NTY;
    const int b = blockIdx.y;

    // window staging source (shared across all 8 parities)
    const unsigned short* srcw = nullptr;
    if (tid < WINR) {
        int wz = tid / (WY * WX);
        int rm = tid - wz * (WY * WX);
        int wy = rm / WX;
        int wx = rm - wy * WX;
        int gz = tz * TZ - 1 + wz, gy = ty * TY - 1 + wy, gx = tx * TX - 1 + wx;
        if ((unsigned)gz < (unsigned)DI && (unsigned)gy < (unsigned)HI &&
            (unsigned)gx < (unsigned)WI) {
            int pin = ((gz & 1) << 2) | ((gy & 1) << 1) | (gx & 1);
            int qin = ((gz >> 1) * HH + (gy >> 1)) * WH + (gx >> 1);
            srcw = xin + (((size_t)pin * 2 + b) * SQI + qin) * CI;
        }
    }

    const int lane = tid & 63;
    const int r15 = lane & 15, l4 = lane >> 4;
    const int w = tid >> 6;  // wave -> parities {2w, 2w+1}
    const int jy = (l4 >> 1) & 1, jx = l4 & 1;

    // per-lane A global pointers (clamped row for CO<BM)
    const unsigned short* aptr[2][MF];
#pragma unroll
    for (int pp = 0; pp < 2; pp++) {
        int p = 2 * w + pp;
#pragma unroll
        for (int mf = 0; mf < MF; mf++) {
            int co = mt * BM + mf * 16 + r15;
            if (co >= CO) co = CO - 1;
            aptr[pp][mf] = Wt + ((size_t)p * CO + co) * (CI * 8) + l4 * 8;
        }
    }

    int poff[2];
#pragma unroll
    for (int pp = 0; pp < 2; pp++) {
        int p = 2 * w + pp;
        poff[pp] = ((p >> 2) * WY + ((p >> 1) & 1)) * WX + (p & 1);
    }
    int baddr0[SF];
#pragma unroll
    for (int sf = 0; sf < SF; sf++) {
        int s = sf * 16 + r15;
        int qxr = s % TX, qyr = (s / TX) % TY, qzr = s / (TX * TY);
        baddr0[sf] = ((qzr + 1) * WY + (qyr + 1 - jy)) * WX + (qxr + 1 - jx);
    }

    f32x4 acc[MF][2 * SF];
#pragma unroll
    for (int mf = 0; mf < MF; mf++) {
        int cobase = mt * BM + mf * 16 + l4 * 4;
        f32x4 bv;
#pragma unroll
        for (int r = 0; r < 4; r++) bv[r] = (cobase + r < CO) ? bias[cobase + r] : 0.f;
#pragma unroll
        for (int nf = 0; nf < 2 * SF; nf++) acc[mf][nf] = bv;
    }

    for (int kt = 0; kt < KT; kt++) {
        __syncthreads();
        if (tid < WINR) {
            short8 v = {0, 0, 0, 0, 0, 0, 0, 0};
            if (srcw) v = *(const short8*)(srcw + kt * 8);
            *(short8*)(lw + tid * 8) = v;
        }
        short8 af[2][MF][2];
#pragma unroll
        for (int pp = 0; pp < 2; pp++)
#pragma unroll
            for (int mf = 0; mf < MF; mf++) {
                const unsigned short* ap = aptr[pp][mf] + kt * 64;
                af[pp][mf][0] = *(const short8*)(ap);
                af[pp][mf][1] = *(const short8*)(ap + 32);
            }
        __syncthreads();
#pragma unroll
        for (int pp = 0; pp < 2; pp++)
#pragma unroll
            for (int sf = 0; sf < SF; sf++) {
                short8 b0 = *(const short8*)(lw + (baddr0[sf] + poff[pp]) * 8);
                short8 b1 = *(const short8*)(lw + (baddr0[sf] + poff[pp] - WY * WX) * 8);
#pragma unroll
                for (int mf = 0; mf < MF; mf++) {
                    acc[mf][pp * SF + sf] = __builtin_amdgcn_mfma_f32_16x16x32_bf16(
                        af[pp][mf][0], b0, acc[mf][pp * SF + sf], 0, 0, 0);
                    acc[mf][pp * SF + sf] = __builtin_amdgcn_mfma_f32_16x16x32_bf16(
                        af[pp][mf][1], b1, acc[mf][pp * SF + sf], 0, 0, 0);
                }
            }
    }

    // epilogue
#pragma unroll
    for (int pp = 0; pp < 2; pp++) {
        int p = 2 * w + pp;
        int pz = p >> 2, py = (p >> 1) & 1, px = p & 1;
#pragma unroll
        for (int sf = 0; sf < SF; sf++) {
            int s = sf * 16 + r15;
            int qx = tx * TX + s % TX;
            int qy = ty * TY + (s / TX) % TY;
            int qz = tz * TZ + s / (TX * TY);
            if constexpr (SIG) {
                if (l4 == 0) {
                    int oz = 2 * qz + pz, oy = 2 * qy + py, ox = 2 * qx + px;
                    float v = acc[0][pp * SF + sf][0];
                    v = 1.f / (1.f + __expf(-v));
                    ((float*)xout)[(size_t)b * (8 * SQO) +
                                   ((size_t)oz * (2 * HI) + oy) * (2 * WI) + ox] = v;
                }
            } else {
                int gq = (qz * HI + qy) * WI + qx;
#pragma unroll
                for (int mf = 0; mf < MF; mf++) {
                    int cobase = mt * BM + mf * 16 + l4 * 4;
                    unsigned long long pk = 0;
#pragma unroll
                    for (int r = 0; r < 4; r++)
                        pk |= (unsigned long long)f2bf(acc[mf][pp * SF + sf][r]) << (16 * r);
                    *(unsigned long long*)((unsigned short*)xout +
                                           (((size_t)p * 2 + b) * SQO + gq) * CO + cobase) = pk;
                }
            }
        }
    }
}

extern "C" void kernel_launch(void* const* d_in, const int* in_sizes, int n_in,
                              void* d_out, int out_size, void* d_ws, size_t ws_size,
                              hipStream_t stream) {
    const float* x_in = (const float*)d_in[0];
    const float* y_in = (const float*)d_in[1];
    const float* tables = (const float*)d_in[2];
    const float* g0 = (const float*)d_in[3];
    const float* be0 = (const float*)d_in[4];
    const float* g1 = (const float*)d_in[5];
    const float* be1 = (const float*)d_in[6];
    const float* g2 = (const float*)d_in[7];
    const float* be2 = (const float*)d_in[8];
    const float* g3 = (const float*)d_in[9];
    const float* be3 = (const float*)d_in[10];
    const float* g4 = (const float*)d_in[11];
    const float* be4 = (const float*)d_in[12];
    const float* w1 = (const float*)d_in[13];
    const float* b1 = (const float*)d_in[14];
    const float* w2 = (const float*)d_in[15];
    const float* b2 = (const float*)d_in[16];
    const float* w3 = (const float*)d_in[17];
    const float* b3 = (const float*)d_in[18];
    const float* w4 = (const float*)d_in[19];
    const float* b4 = (const float*)d_in[20];
    const float* w5 = (const float*)d_in[21];
    const float* b5 = (const float*)d_in[22];
    float* out = (float*)d_out;

    char* base = (char*)d_ws;
    size_t off = 0;
    auto alloc = [&](size_t bytes) -> void* {
        void* r = base + off;
        off += (bytes + 255) & ~(size_t)255;
        return r;
    };
    float* wproj = (float*)alloc(8388608);
    unsigned short* x0 = (unsigned short*)alloc(786432);
    unsigned short* x1 = (unsigned short*)alloc(3145728);
    unsigned short* x2 = (unsigned short*)alloc(12582912);
    unsigned short* x3 = (unsigned short*)alloc(50331648);
    unsigned short* x4 = (unsigned short*)alloc(100663296);
    unsigned short* Wt1 = (unsigned short*)alloc(67108864);
    unsigned short* Wt2 = (unsigned short*)alloc(16777216);
    unsigned short* Wt3 = (unsigned short*)alloc(4194304);
    unsigned short* Wt4 = (unsigned short*)alloc(524288);
    unsigned short* Wt5 = (unsigned short*)alloc(4096);
    float* sums = (float*)alloc(8192);
    float* sc = (float*)alloc(4096);
    float* sh = (float*)alloc(4096);

    hyper_k<<<4096, 256, 0, stream>>>(y_in, tables, wproj);
    conv0_k<<<dim3(1024, 2), 256, 0, stream>>>(x_in, wproj, x0);

    wt_k<512, 1024><<<16384, 256, 0, stream>>>(w1, Wt1);
    wt_k<256, 512><<<4096, 256, 0, stream>>>(w2, Wt2);
    wt_k<128, 256><<<1024, 256, 0, stream>>>(w3, Wt3);
    wt_k<32, 128><<<128, 256, 0, stream>>>(w4, Wt4);
    wt_k<1, 32><<<1, 256, 0, stream>>>(w5, Wt5);

    // BN0: C=1024, R=384
    hipMemsetAsync(sums, 0, 2 * 1024 * 4, stream);
    bnstats3_k<1024><<<192, 256, 0, stream>>>(x0, sums, 384);
    bnfinal_k<<<4, 256, 0, stream>>>(sums, g0, be0, sc, sh, 1024, 1.f / 384);
    bnapply2_k<<<192, 256, 0, stream>>>(x0, sc, sh, 1024, 49152);
    convt_mfma<512, 1024, 4, 6, 8, 4, 2, 8, 4, 32, false>
        <<<dim3(12, 8, 2), 256, 0, stream>>>(x0, Wt1, b1, x1);

    // BN1: C=512, R=3072
    hipMemsetAsync(sums, 0, 2 * 512 * 4, stream);
    bnstats3_k<512><<<512, 256, 0, stream>>>(x1, sums, 3072);
    bnfinal_k<<<2, 256, 0, stream>>>(sums, g1, be1, sc, sh, 512, 1.f / 3072);
    bnapply2_k<<<768, 256, 0, stream>>>(x1, sc, sh, 512, 196608);
    convt_mfma<256, 512, 8, 12, 16, 8, 4, 8, 1, 32, false>
        <<<dim3(48, 8, 2), 256, 0, stream>>>(x1, Wt2, b2, x2);

    // BN2: C=256, R=24576
    hipMemsetAsync(sums, 0, 2 * 256 * 4, stream);
    bnstats3_k<256><<<512, 256, 0, stream>>>(x2, sums, 24576);
    bnfinal_k<<<1, 256, 0, stream>>>(sums, g2, be2, sc, sh, 256, 1.f / 24576);
    bnapply2_k<<<3072, 256, 0, stream>>>(x2, sc, sh, 256, 786432);
    convt_mfma<128, 256, 16, 24, 32, 8, 4, 8, 1, 32, false>
        <<<dim3(192, 8, 2), 256, 0, stream>>>(x2, Wt3, b3, x3);

    // BN3: C=128, R=196608
    hipMemsetAsync(sums, 0, 2 * 128 * 4, stream);
    bnstats3_k<128><<<512, 256, 0, stream>>>(x3, sums, 196608);
    bnfinal_k<<<1, 256, 0, stream>>>(sums, g3, be3, sc, sh, 128, 1.f / 196608);
    bnapply2_k<<<12288, 256, 0, stream>>>(x3, sc, sh, 128, 3145728);
    // stage 4: shared-window, all 8 parities per block
    convt_mfma2<32, 128, 32, 48, 64, 2, 4, 8, 32, false>
        <<<dim3(1536, 2), 256, 0, stream>>>(x3, Wt4, b4, x4);

    // BN4: C=32, R=1572864
    hipMemsetAsync(sums, 0, 2 * 32 * 4, stream);
    bnstats3_k<32><<<512, 256, 0, stream>>>(x4, sums, 1572864);
    bnfinal_k<<<1, 256, 0, stream>>>(sums, g4, be4, sc, sh, 32, 1.f / 1572864);
    bnapply2_k<<<24576, 256, 0, stream>>>(x4, sc, sh, 32, 6291456);
    // stage 5: shared-window, sigmoid f32 epilogue
    convt_mfma2<1, 32, 64, 96, 128, 2, 4, 8, 16, true>
        <<<dim3(12288, 2), 256, 0, stream>>>(x4, Wt5, b5, out);
}